// Round 6
// baseline (764.381 us; speedup 1.0000x reference)
//
#include <hip/hip_runtime.h>
#include <hip/hip_bf16.h>

#define NN 100000
#define DD 64
#define EE 400000
#define TT 5

#define SCAN_TOTAL 500000   /* T*N */
#define SCAN_T 256
#define SCAN_PER 1024       /* 256 threads x 4 elems */
#define SCAN_B 512          /* 512*1024 = 524288 >= 500000 */

#define CH 64               /* node chunks per t (exclusive bin ownership) */
#define BPC 1563            /* ceil(NN/CH) bins per chunk */

typedef __bf16 bf16x8 __attribute__((ext_vector_type(8)));
typedef float  f32x4  __attribute__((ext_vector_type(4)));

// ws layout (bytes)
#define OFF_XBF 0u            // N*D ushort        = 12,800,000
#define OFF_WT  12800000u     // T*64*128 ushort   = 81,920
#define OFF_CNT 12881920u     // T*N u32           = 2,000,000
#define OFF_WGT 14881920u     // T f32 (pad 64)
#define OFF_CUR 14881984u     // 524288 u32        = 2,097,152
#define OFF_BS  16979136u     // 512 u32 (pad 2048)
#define OFF_BO  16981184u     // 512 u32 (pad 2048)
#define OFF_DST 16983232u     // 2M int (sorted dst) = 8,000,000
#define OFF_SEG 24983232u     // 2M int (seg src)    = 8,000,000

__device__ __forceinline__ unsigned short f2bf(float f) {
    union { float f; unsigned u; } v; v.f = f;
    unsigned u = v.u;
    return (unsigned short)((u + 0x7FFFu + ((u >> 16) & 1u)) >> 16);  // RNE
}

// ---------------- Phase 1: init / convert ----------------
__global__ void k_init(const float* __restrict__ x, const float* __restrict__ W,
                       const float* __restrict__ ea,
                       unsigned short* __restrict__ xbf, unsigned short* __restrict__ wT,
                       float* __restrict__ wgt, float* __restrict__ out) {
    int i = blockIdx.x * blockDim.x + threadIdx.x;   // grid covers N*D exactly
    if (i < NN * DD) {
        out[i] = 0.0f;
        xbf[i] = f2bf(x[i]);
    }
    if (i < TT * 128 * 64) {
        int t = i >> 13;          // /8192
        int rem = i & 8191;
        int d = rem >> 7;         // /128
        int k = rem & 127;
        wT[i] = f2bf(W[t * 8192 + k * 64 + d]);   // wT[t][d][k] = W[t][k][d]
    }
    if (i == 0) {
        float m = -1e30f;
        for (int t = 0; t < TT; t++) m = fmaxf(m, ea[t]);
        float e[TT]; float s = 0.0f;
        for (int t = 0; t < TT; t++) { e[t] = __expf(ea[t] - m); s += e[t]; }
        for (int t = 0; t < TT; t++) wgt[t] = e[t] / s;
    }
}

// ---------------- Phase 2: chunk-owned degree counts (NO global atomics).
// Block (chunk,t) owns bins [lo,hi); streams the whole t-src array (L2-hot,
// 8 MB distinct device-wide) and histograms in LDS. Scattered device atomics
// ran at ~17 G/s (R3/R5 lesson) — this replaces 2M of them. ----------------
__global__ __launch_bounds__(256) void k_count_c(const int* __restrict__ edges,
                                                 unsigned* __restrict__ counts) {
    const int chunk = blockIdx.x, t = blockIdx.y;
    const int lo = chunk * BPC;
    const int hi = min(lo + BPC, NN);
    __shared__ unsigned hist[BPC];
    for (int i = threadIdx.x; i < BPC; i += 256) hist[i] = 0u;
    __syncthreads();
    const int4* srcp = reinterpret_cast<const int4*>(edges + (size_t)t * 2 * EE);
    for (int i = threadIdx.x; i < EE / 4; i += 256) {
        int4 v = srcp[i];
        if (v.x >= lo && v.x < hi) atomicAdd(&hist[v.x - lo], 1u);
        if (v.y >= lo && v.y < hi) atomicAdd(&hist[v.y - lo], 1u);
        if (v.z >= lo && v.z < hi) atomicAdd(&hist[v.z - lo], 1u);
        if (v.w >= lo && v.w < hi) atomicAdd(&hist[v.w - lo], 1u);
    }
    __syncthreads();
    for (int i = threadIdx.x; i < hi - lo; i += 256)
        counts[t * NN + lo + i] = hist[i];   // coalesced plain stores
}

// ---------------- Phase 2b: exclusive scan of counts (2 kernels; block
// offsets boff[] folded in at use) ----------------
__global__ void k_scan1(const unsigned* __restrict__ cnt, unsigned* __restrict__ cur,
                        unsigned* __restrict__ bsum) {
    __shared__ unsigned s[SCAN_T];
    const int b = blockIdx.x, tid = threadIdx.x;
    const int base = b * SCAN_PER + tid * 4;
    uint4 v = make_uint4(0u, 0u, 0u, 0u);
    if (base + 3 < SCAN_TOTAL) {
        v = *reinterpret_cast<const uint4*>(cnt + base);
    } else {
        if (base + 0 < SCAN_TOTAL) v.x = cnt[base + 0];
        if (base + 1 < SCAN_TOTAL) v.y = cnt[base + 1];
        if (base + 2 < SCAN_TOTAL) v.z = cnt[base + 2];
        if (base + 3 < SCAN_TOTAL) v.w = cnt[base + 3];
    }
    const unsigned tsum = v.x + v.y + v.z + v.w;
    s[tid] = tsum;
    __syncthreads();
    unsigned inc = tsum;
    for (int d = 1; d < SCAN_T; d <<= 1) {
        unsigned add = (tid >= d) ? s[tid - d] : 0u;
        __syncthreads();
        inc += add;
        s[tid] = inc;
        __syncthreads();
    }
    if (tid == SCAN_T - 1) bsum[b] = inc;
    const unsigned p0 = inc - tsum;
    const unsigned p1 = p0 + v.x, p2 = p1 + v.y, p3 = p2 + v.z;
    if (base + 3 < SCAN_TOTAL) {
        *reinterpret_cast<uint4*>(cur + base) = make_uint4(p0, p1, p2, p3);
    } else {
        if (base + 0 < SCAN_TOTAL) cur[base + 0] = p0;
        if (base + 1 < SCAN_TOTAL) cur[base + 1] = p1;
        if (base + 2 < SCAN_TOTAL) cur[base + 2] = p2;
        if (base + 3 < SCAN_TOTAL) cur[base + 3] = p3;
    }
}

__global__ void k_scan2(const unsigned* __restrict__ bsum, unsigned* __restrict__ boff) {
    __shared__ unsigned s[SCAN_B];
    const int tid = threadIdx.x;
    const unsigned v = bsum[tid];
    s[tid] = v;
    __syncthreads();
    unsigned inc = v;
    for (int d = 1; d < SCAN_B; d <<= 1) {
        unsigned add = (tid >= d) ? s[tid - d] : 0u;
        __syncthreads();
        inc += add;
        s[tid] = inc;
        __syncthreads();
    }
    boff[tid] = inc - v;
}

// ---------------- Phase 2c: chunk-owned fill. Positions via LDS atomicAdd on
// the chunk's scan bases; writes land in the chunk's CONTIGUOUS output
// window (~25 KB) — L2-local, not fabric-scattered. Global cur[] untouched. --
__global__ __launch_bounds__(256) void k_fill_c(const int* __restrict__ edges,
                                                const unsigned* __restrict__ cur,
                                                const unsigned* __restrict__ boff,
                                                int* __restrict__ sdst) {
    const int chunk = blockIdx.x, t = blockIdx.y;
    const int lo = chunk * BPC;
    const int hi = min(lo + BPC, NN);
    __shared__ unsigned curl[BPC];
    for (int i = threadIdx.x; i < hi - lo; i += 256) {
        int g = t * NN + lo + i;
        curl[i] = cur[g] + boff[g >> 10];
    }
    __syncthreads();
    const int* srcp = edges + (size_t)t * 2 * EE;
    const int* dstp = srcp + EE;
    for (int i = threadIdx.x; i < EE / 4; i += 256) {
        int4 v = reinterpret_cast<const int4*>(srcp)[i];
        int e = i * 4;
        if (v.x >= lo && v.x < hi) sdst[atomicAdd(&curl[v.x - lo], 1u)] = dstp[e + 0];
        if (v.y >= lo && v.y < hi) sdst[atomicAdd(&curl[v.y - lo], 1u)] = dstp[e + 1];
        if (v.z >= lo && v.z < hi) sdst[atomicAdd(&curl[v.z - lo], 1u)] = dstp[e + 2];
        if (v.w >= lo && v.w < hi) sdst[atomicAdd(&curl[v.w - lo], 1u)] = dstp[e + 3];
    }
}

// ---------------- Phase 2d: materialize per-position src (COALESCED writes) --
__global__ void k_seg(const unsigned* __restrict__ cur, const unsigned* __restrict__ boff,
                      const unsigned* __restrict__ cnt, int* __restrict__ seg) {
    int i = blockIdx.x * blockDim.x + threadIdx.x;
    if (i >= TT * NN) return;
    unsigned c = cnt[i];
    if (!c) return;
    unsigned start = cur[i] + boff[i >> 10];   // global exclusive-scan base
    int s = i % NN;
    for (unsigned j = 0; j < c; j++) seg[start + j] = s;
}

// ---------------- Phase 3: gather -> MFMA -> wave-cooperative segmented scatter ----------------
__global__ __launch_bounds__(256) void k_edge(
    const unsigned short* __restrict__ xbf, const unsigned short* __restrict__ wT,
    const float* __restrict__ b, const int* __restrict__ sdst,
    const int* __restrict__ seg, const unsigned* __restrict__ cnt,
    const float* __restrict__ wgt, float* __restrict__ out) {
    const int t  = blockIdx.y;
    const int e0 = blockIdx.x * 128;

    __shared__ __align__(16) unsigned short Ab[128][136];   // feats tile; reused as f32 proj[128][68]
    __shared__ __align__(16) unsigned short Bb[64][136];    // W_t^T [d][k]
    __shared__ float scale_s[128];
    __shared__ int   src_s[132];                             // padded

    const int tid = threadIdx.x;

    // stage B: W_t^T is 64x128 bf16 contiguous in ws
    {
        const unsigned short* src = wT + (size_t)t * 8192;
        int d = tid >> 2, seg4 = tid & 3;                      // 64B per thread
        const float4* g = reinterpret_cast<const float4*>(src + d * 128 + seg4 * 32);
        float4* l = reinterpret_cast<float4*>(&Bb[d][seg4 * 32]);
#pragma unroll
        for (int c = 0; c < 4; c++) l[c] = g[c];
    }
    // stage A: gather x rows (bf16, 128B each); thread pair per sorted edge
    {
        int e = tid >> 1, half = tid & 1;
        size_t pos = (size_t)t * EE + e0 + e;
        int idx = half ? sdst[pos] : seg[pos];
        const float4* g = reinterpret_cast<const float4*>(xbf + (size_t)idx * 64);
        float4* l = reinterpret_cast<float4*>(&Ab[e][half * 64]);
#pragma unroll
        for (int c = 0; c < 8; c++) l[c] = g[c];
        if (half == 0) {
            src_s[e] = idx;
            scale_s[e] = wgt[t] / (float)cnt[t * NN + idx];   // counts table is L2-hot
        }
    }
    __syncthreads();

    const int wv = tid >> 6, lane = tid & 63;
    const int m16 = lane & 15, quad = lane >> 4;

    f32x4 acc[2][4];
#pragma unroll
    for (int tm = 0; tm < 2; tm++)
#pragma unroll
        for (int tn = 0; tn < 4; tn++)
            acc[tm][tn] = (f32x4){0.f, 0.f, 0.f, 0.f};

#pragma unroll
    for (int kk = 0; kk < 128; kk += 32) {
        const int kb = kk + quad * 8;
        bf16x8 af[2], bfr[4];
#pragma unroll
        for (int tm = 0; tm < 2; tm++)
            af[tm] = *reinterpret_cast<const bf16x8*>(&Ab[wv * 32 + tm * 16 + m16][kb]);
#pragma unroll
        for (int tn = 0; tn < 4; tn++)
            bfr[tn] = *reinterpret_cast<const bf16x8*>(&Bb[tn * 16 + m16][kb]);
#pragma unroll
        for (int tm = 0; tm < 2; tm++)
#pragma unroll
            for (int tn = 0; tn < 4; tn++)
                acc[tm][tn] = __builtin_amdgcn_mfma_f32_16x16x32_bf16(
                    af[tm], bfr[tn], acc[tm][tn], 0, 0, 0);
    }

    // all waves done reading Ab before we overwrite it with f32 proj
    __syncthreads();

    float bias[4];
#pragma unroll
    for (int tn = 0; tn < 4; tn++) bias[tn] = b[t * 64 + tn * 16 + m16];

    float* proj = reinterpret_cast<float*>(&Ab[0][0]);   // [128][68] f32, stride 68
#pragma unroll
    for (int tm = 0; tm < 2; tm++) {
#pragma unroll
        for (int r = 0; r < 4; r++) {
            const int eloc = wv * 32 + tm * 16 + quad * 4 + r;   // in [wv*32, wv*32+32)
            const float s = scale_s[eloc];
#pragma unroll
            for (int tn = 0; tn < 4; tn++) {
                float v = acc[tm][tn][r] + bias[tn];
                v = v > 0.f ? v : 0.f;
                proj[eloc * 68 + tn * 16 + m16] = v * s;
            }
        }
    }
    // NO barrier: wave wv wrote exactly proj rows [wv*32, wv*32+32) and reads
    // only those below. (src_s/scale_s were synced by the earlier barrier.)

    // wave-cooperative segmented reduce: lane = feature, walk 32 sorted edges,
    // flush one COALESCED 256B atomic burst per segment. Atomics cost their
    // fabric-line footprint, not their op count (R1 vs R3 lesson).
    {
        const int j0 = wv * 32;
        float sum = 0.f;
#pragma unroll
        for (int j = j0; j < j0 + 32; j++) {
            sum += proj[j * 68 + lane];
            const bool flush = (j == j0 + 31) || (src_s[j + 1] != src_s[j]);
            if (flush) {
                atomicAdd(out + (size_t)src_s[j] * 64 + lane, sum);
                sum = 0.f;
            }
        }
    }
}

extern "C" void kernel_launch(void* const* d_in, const int* in_sizes, int n_in,
                              void* d_out, int out_size, void* d_ws, size_t ws_size,
                              hipStream_t stream) {
    const float* x     = (const float*)d_in[0];
    const float* W     = (const float*)d_in[1];
    const float* b     = (const float*)d_in[2];
    const float* ea    = (const float*)d_in[3];
    const int*   edges = (const int*)d_in[4];
    float* out = (float*)d_out;

    char* ws = (char*)d_ws;
    unsigned short* xbf = (unsigned short*)(ws + OFF_XBF);
    unsigned short* wT  = (unsigned short*)(ws + OFF_WT);
    unsigned* counts    = (unsigned*)(ws + OFF_CNT);
    float* wgt          = (float*)(ws + OFF_WGT);
    unsigned* cur       = (unsigned*)(ws + OFF_CUR);
    unsigned* bsum      = (unsigned*)(ws + OFF_BS);
    unsigned* boff      = (unsigned*)(ws + OFF_BO);
    int* sdst           = (int*)(ws + OFF_DST);
    int* seg            = (int*)(ws + OFF_SEG);

    // Phase 1: out-zero, x->bf16, W^T, softmax (counts no longer need zeroing)
    k_init<<<(NN * DD) / 256, 256, 0, stream>>>(x, W, ea, xbf, wT, wgt, out);

    // Phase 2: chunk-owned histogram counts (no global atomics)
    dim3 gC(CH, TT);
    k_count_c<<<gC, 256, 0, stream>>>(edges, counts);

    // Phase 2b: exclusive scan counts -> cur (block-local) + boff
    k_scan1<<<SCAN_B, SCAN_T, 0, stream>>>(counts, cur, bsum);
    k_scan2<<<1, SCAN_B, 0, stream>>>(bsum, boff);

    // Phase 2c: chunk-owned counting-sort fill (LDS position counters)
    k_fill_c<<<gC, 256, 0, stream>>>(edges, cur, boff, sdst);

    // Phase 2d: per-position src, coalesced writes
    k_seg<<<(TT * NN + 255) / 256, 256, 0, stream>>>(cur, boff, counts, seg);

    // Phase 3: MFMA gather-GEMM + wave-cooperative segmented scatter
    dim3 grid(EE / 128, TT);
    k_edge<<<grid, 256, 0, stream>>>(xbf, wT, b, sdst, seg, counts, wgt, out);
}

// Round 7
// 462.201 us; speedup vs baseline: 1.6538x; 1.6538x over previous
//
#include <hip/hip_runtime.h>
#include <hip/hip_bf16.h>

#define NN 100000
#define DD 64
#define EE 400000
#define TT 5

#define NSPLIT 4                 /* edge-stream splits (inner sort key) */
#define ESL (EE / NSPLIT)        /* 100,000 edges per split slice */
#define CH 32                    /* node chunks per t (exclusive bin ownership) */
#define BPC 3125                 /* NN/CH exact */

#define SCAN_TOTAL2 (TT * NN * NSPLIT)   /* 2,000,000 */
#define SCAN_T 256
#define SCAN_PER 1024            /* 256 threads x 4 */
#define SCAN_B2 1954             /* ceil(2,000,000/1024) */

typedef __bf16 bf16x8 __attribute__((ext_vector_type(8)));
typedef float  f32x4  __attribute__((ext_vector_type(4)));

// ws layout (bytes) — total ~38.9 MB (R4's 41 MB proven safe)
#define OFF_XBF  0u            // N*D ushort      = 12,800,000
#define OFF_WT   12800000u     // T*64*128 ushort = 81,920
#define OFF_CTOT 12881920u     // T*N u32 (cnt_tot) = 2,000,000
#define OFF_WGT  14881920u     // T f32 (pad 64)
#define OFF_CNT2 14881984u     // T*N*NSPLIT u32  = 8,000,000 (in-place scan -> cur2)
#define OFF_BS   22881984u     // 1954 u32 (pad 8192)
#define OFF_BO   22890176u     // 1954 u32 (pad 8192)
#define OFF_DST  22898368u     // 2M int (sorted dst) = 8,000,000
#define OFF_SEG  30898368u     // 2M int (seg src)    = 8,000,000  -> ends 38,898,368

__device__ __forceinline__ unsigned short f2bf(float f) {
    union { float f; unsigned u; } v; v.f = f;
    unsigned u = v.u;
    return (unsigned short)((u + 0x7FFFu + ((u >> 16) & 1u)) >> 16);  // RNE
}

// ---------------- Phase 1: init / convert ----------------
__global__ void k_init(const float* __restrict__ x, const float* __restrict__ W,
                       const float* __restrict__ ea,
                       unsigned short* __restrict__ xbf, unsigned short* __restrict__ wT,
                       float* __restrict__ wgt, float* __restrict__ out) {
    int i = blockIdx.x * blockDim.x + threadIdx.x;   // grid covers N*D exactly
    if (i < NN * DD) {
        out[i] = 0.0f;
        xbf[i] = f2bf(x[i]);
    }
    if (i < TT * 128 * 64) {
        int t = i >> 13;          // /8192
        int rem = i & 8191;
        int d = rem >> 7;         // /128
        int k = rem & 127;
        wT[i] = f2bf(W[t * 8192 + k * 64 + d]);   // wT[t][d][k] = W[t][k][d]
    }
    if (i == 0) {
        float m = -1e30f;
        for (int t = 0; t < TT; t++) m = fmaxf(m, ea[t]);
        float e[TT]; float s = 0.0f;
        for (int t = 0; t < TT; t++) { e[t] = __expf(ea[t] - m); s += e[t]; }
        for (int t = 0; t < TT; t++) wgt[t] = e[t] / s;
    }
}

// ---------------- Phase 2: chunk+split histogram (no global atomics).
// Block (chunk, split, t) owns bins [lo,hi) x its split slice of the edge
// stream. R6 lesson: same structure at 320 blocks was LATENCY-bound (1.25
// blk/CU, 390-iter chains) — 640 blocks x 98-iter chains fixes occupancy. ----
__global__ __launch_bounds__(256) void k_count_c(const int* __restrict__ edges,
                                                 unsigned* __restrict__ cnt2) {
    const int chunk = blockIdx.x, split = blockIdx.y, t = blockIdx.z;
    const int lo = chunk * BPC;          // hi = lo + BPC exactly (32*3125 = NN)
    __shared__ unsigned hist[BPC];
    for (int i = threadIdx.x; i < BPC; i += 256) hist[i] = 0u;
    __syncthreads();
    const int4* srcp = reinterpret_cast<const int4*>(edges + (size_t)t * 2 * EE + split * ESL);
    for (int i = threadIdx.x; i < ESL / 4; i += 256) {
        int4 v = srcp[i];
        unsigned ux = v.x - lo, uy = v.y - lo, uz = v.z - lo, uw = v.w - lo;
        if (ux < BPC) atomicAdd(&hist[ux], 1u);
        if (uy < BPC) atomicAdd(&hist[uy], 1u);
        if (uz < BPC) atomicAdd(&hist[uz], 1u);
        if (uw < BPC) atomicAdd(&hist[uw], 1u);
    }
    __syncthreads();
    for (int i = threadIdx.x; i < BPC; i += 256)
        cnt2[((size_t)t * NN + lo + i) * NSPLIT + split] = hist[i];
}

// ---------------- Phase 2b: exclusive scan over (t,src,split)-flattened cnt2.
// In-place (cnt2 -> block-local prefixes), boff folded at use. ----------------
__global__ void k_scan1(const unsigned* __restrict__ cnt, unsigned* __restrict__ cur,
                        unsigned* __restrict__ bsum) {
    __shared__ unsigned s[SCAN_T];
    const int b = blockIdx.x, tid = threadIdx.x;
    const int base = b * SCAN_PER + tid * 4;
    uint4 v = make_uint4(0u, 0u, 0u, 0u);
    if (base + 3 < SCAN_TOTAL2) v = *reinterpret_cast<const uint4*>(cnt + base);
    const unsigned tsum = v.x + v.y + v.z + v.w;
    s[tid] = tsum;
    __syncthreads();
    unsigned inc = tsum;
    for (int d = 1; d < SCAN_T; d <<= 1) {
        unsigned add = (tid >= d) ? s[tid - d] : 0u;
        __syncthreads();
        inc += add;
        s[tid] = inc;
        __syncthreads();
    }
    if (tid == SCAN_T - 1) bsum[b] = inc;
    const unsigned p0 = inc - tsum;
    if (base + 3 < SCAN_TOTAL2) {
        *reinterpret_cast<uint4*>(cur + base) =
            make_uint4(p0, p0 + v.x, p0 + v.x + v.y, p0 + v.x + v.y + v.z);
    }
}

__global__ void k_scan2(const unsigned* __restrict__ bsum, unsigned* __restrict__ boff) {
    __shared__ unsigned s[SCAN_T];
    const int tid = threadIdx.x;
    unsigned loc[8];
    unsigned tsum = 0u;
#pragma unroll
    for (int j = 0; j < 8; j++) {
        int idx = tid * 8 + j;
        unsigned v = (idx < SCAN_B2) ? bsum[idx] : 0u;
        loc[j] = tsum;
        tsum += v;
    }
    s[tid] = tsum;
    __syncthreads();
    unsigned inc = tsum;
    for (int d = 1; d < SCAN_T; d <<= 1) {
        unsigned add = (tid >= d) ? s[tid - d] : 0u;
        __syncthreads();
        inc += add;
        s[tid] = inc;
        __syncthreads();
    }
    const unsigned base = inc - tsum;
#pragma unroll
    for (int j = 0; j < 8; j++) {
        int idx = tid * 8 + j;
        if (idx < SCAN_B2) boff[idx] = base + loc[j];
    }
}

// ---------------- Phase 2c: chunk+split fill. Exclusive (bin,split) ownership
// -> LDS position counters; writes land in contiguous per-(t,chunk) windows. --
__global__ __launch_bounds__(256) void k_fill_c(const int* __restrict__ edges,
                                                const unsigned* __restrict__ cur2,
                                                const unsigned* __restrict__ boff,
                                                int* __restrict__ sdst) {
    const int chunk = blockIdx.x, split = blockIdx.y, t = blockIdx.z;
    const int lo = chunk * BPC;
    __shared__ unsigned curl[BPC];
    for (int i = threadIdx.x; i < BPC; i += 256) {
        size_t f = ((size_t)t * NN + lo + i) * NSPLIT + split;
        curl[i] = cur2[f] + boff[f >> 10];
    }
    __syncthreads();
    const int* srcp = edges + (size_t)t * 2 * EE + split * ESL;
    const int* dstp = srcp + EE;   // dst plane is +EE from src plane
    for (int i = threadIdx.x; i < ESL / 4; i += 256) {
        int4 v = reinterpret_cast<const int4*>(srcp)[i];
        int e = i * 4;
        unsigned ux = v.x - lo, uy = v.y - lo, uz = v.z - lo, uw = v.w - lo;
        if (ux < BPC) sdst[atomicAdd(&curl[ux], 1u)] = dstp[e + 0];
        if (uy < BPC) sdst[atomicAdd(&curl[uy], 1u)] = dstp[e + 1];
        if (uz < BPC) sdst[atomicAdd(&curl[uz], 1u)] = dstp[e + 2];
        if (uw < BPC) sdst[atomicAdd(&curl[uw], 1u)] = dstp[e + 3];
    }
}

// ---------------- Phase 2d: per-position src + cnt_tot from scan differences --
__global__ void k_seg(const unsigned* __restrict__ cur2, const unsigned* __restrict__ boff,
                      int* __restrict__ seg, unsigned* __restrict__ cnt_tot) {
    int i = blockIdx.x * blockDim.x + threadIdx.x;
    if (i >= TT * NN) return;
    size_t f0 = (size_t)i * NSPLIT;
    unsigned start = cur2[f0] + boff[f0 >> 10];
    unsigned end;
    if (i == TT * NN - 1) end = TT * EE;
    else {
        size_t f1 = f0 + NSPLIT;
        end = cur2[f1] + boff[f1 >> 10];
    }
    unsigned c = end - start;
    cnt_tot[i] = c;
    int s = i % NN;
    for (unsigned j = start; j < end; j++) seg[j] = s;
}

// ---------------- Phase 3: gather -> MFMA -> wave-cooperative segmented scatter
// (UNCHANGED from R5 — 185 µs, WRITE 134 MB) ----------------
__global__ __launch_bounds__(256) void k_edge(
    const unsigned short* __restrict__ xbf, const unsigned short* __restrict__ wT,
    const float* __restrict__ b, const int* __restrict__ sdst,
    const int* __restrict__ seg, const unsigned* __restrict__ cnt,
    const float* __restrict__ wgt, float* __restrict__ out) {
    const int t  = blockIdx.y;
    const int e0 = blockIdx.x * 128;

    __shared__ __align__(16) unsigned short Ab[128][136];   // feats tile; reused as f32 proj[128][68]
    __shared__ __align__(16) unsigned short Bb[64][136];    // W_t^T [d][k]
    __shared__ float scale_s[128];
    __shared__ int   src_s[132];                             // padded

    const int tid = threadIdx.x;

    // stage B: W_t^T is 64x128 bf16 contiguous in ws
    {
        const unsigned short* src = wT + (size_t)t * 8192;
        int d = tid >> 2, seg4 = tid & 3;                      // 64B per thread
        const float4* g = reinterpret_cast<const float4*>(src + d * 128 + seg4 * 32);
        float4* l = reinterpret_cast<float4*>(&Bb[d][seg4 * 32]);
#pragma unroll
        for (int c = 0; c < 4; c++) l[c] = g[c];
    }
    // stage A: gather x rows (bf16, 128B each); thread pair per sorted edge
    {
        int e = tid >> 1, half = tid & 1;
        size_t pos = (size_t)t * EE + e0 + e;
        int idx = half ? sdst[pos] : seg[pos];
        const float4* g = reinterpret_cast<const float4*>(xbf + (size_t)idx * 64);
        float4* l = reinterpret_cast<float4*>(&Ab[e][half * 64]);
#pragma unroll
        for (int c = 0; c < 8; c++) l[c] = g[c];
        if (half == 0) {
            src_s[e] = idx;
            scale_s[e] = wgt[t] / (float)cnt[t * NN + idx];   // cnt_tot table is L2-hot
        }
    }
    __syncthreads();

    const int wv = tid >> 6, lane = tid & 63;
    const int m16 = lane & 15, quad = lane >> 4;

    f32x4 acc[2][4];
#pragma unroll
    for (int tm = 0; tm < 2; tm++)
#pragma unroll
        for (int tn = 0; tn < 4; tn++)
            acc[tm][tn] = (f32x4){0.f, 0.f, 0.f, 0.f};

#pragma unroll
    for (int kk = 0; kk < 128; kk += 32) {
        const int kb = kk + quad * 8;
        bf16x8 af[2], bfr[4];
#pragma unroll
        for (int tm = 0; tm < 2; tm++)
            af[tm] = *reinterpret_cast<const bf16x8*>(&Ab[wv * 32 + tm * 16 + m16][kb]);
#pragma unroll
        for (int tn = 0; tn < 4; tn++)
            bfr[tn] = *reinterpret_cast<const bf16x8*>(&Bb[tn * 16 + m16][kb]);
#pragma unroll
        for (int tm = 0; tm < 2; tm++)
#pragma unroll
            for (int tn = 0; tn < 4; tn++)
                acc[tm][tn] = __builtin_amdgcn_mfma_f32_16x16x32_bf16(
                    af[tm], bfr[tn], acc[tm][tn], 0, 0, 0);
    }

    // all waves done reading Ab before we overwrite it with f32 proj
    __syncthreads();

    float bias[4];
#pragma unroll
    for (int tn = 0; tn < 4; tn++) bias[tn] = b[t * 64 + tn * 16 + m16];

    float* proj = reinterpret_cast<float*>(&Ab[0][0]);   // [128][68] f32, stride 68
#pragma unroll
    for (int tm = 0; tm < 2; tm++) {
#pragma unroll
        for (int r = 0; r < 4; r++) {
            const int eloc = wv * 32 + tm * 16 + quad * 4 + r;   // in [wv*32, wv*32+32)
            const float s = scale_s[eloc];
#pragma unroll
            for (int tn = 0; tn < 4; tn++) {
                float v = acc[tm][tn][r] + bias[tn];
                v = v > 0.f ? v : 0.f;
                proj[eloc * 68 + tn * 16 + m16] = v * s;
            }
        }
    }
    // NO barrier: wave wv wrote exactly proj rows [wv*32, wv*32+32) and reads
    // only those below. (src_s/scale_s were synced by the earlier barrier.)

    // wave-cooperative segmented reduce: lane = feature, walk 32 sorted edges,
    // flush one COALESCED 256B atomic burst per segment. Atomics cost their
    // fabric-line footprint, not their op count (R1 vs R3 lesson).
    {
        const int j0 = wv * 32;
        float sum = 0.f;
#pragma unroll
        for (int j = j0; j < j0 + 32; j++) {
            sum += proj[j * 68 + lane];
            const bool flush = (j == j0 + 31) || (src_s[j + 1] != src_s[j]);
            if (flush) {
                atomicAdd(out + (size_t)src_s[j] * 64 + lane, sum);
                sum = 0.f;
            }
        }
    }
}

extern "C" void kernel_launch(void* const* d_in, const int* in_sizes, int n_in,
                              void* d_out, int out_size, void* d_ws, size_t ws_size,
                              hipStream_t stream) {
    const float* x     = (const float*)d_in[0];
    const float* W     = (const float*)d_in[1];
    const float* b     = (const float*)d_in[2];
    const float* ea    = (const float*)d_in[3];
    const int*   edges = (const int*)d_in[4];
    float* out = (float*)d_out;

    char* ws = (char*)d_ws;
    unsigned short* xbf = (unsigned short*)(ws + OFF_XBF);
    unsigned short* wT  = (unsigned short*)(ws + OFF_WT);
    unsigned* cnt_tot   = (unsigned*)(ws + OFF_CTOT);
    float* wgt          = (float*)(ws + OFF_WGT);
    unsigned* cnt2      = (unsigned*)(ws + OFF_CNT2);   // becomes cur2 after in-place scan
    unsigned* bsum      = (unsigned*)(ws + OFF_BS);
    unsigned* boff      = (unsigned*)(ws + OFF_BO);
    int* sdst           = (int*)(ws + OFF_DST);
    int* seg            = (int*)(ws + OFF_SEG);

    // Phase 1: out-zero, x->bf16, W^T, softmax
    k_init<<<(NN * DD) / 256, 256, 0, stream>>>(x, W, ea, xbf, wT, wgt, out);

    // Phase 2: chunk+split histogram counts (no global atomics, 640 blocks)
    dim3 gC(CH, NSPLIT, TT);
    k_count_c<<<gC, 256, 0, stream>>>(edges, cnt2);

    // Phase 2b: in-place exclusive scan of cnt2 (block-local) + boff
    k_scan1<<<SCAN_B2, SCAN_T, 0, stream>>>(cnt2, cnt2, bsum);
    k_scan2<<<1, SCAN_T, 0, stream>>>(bsum, boff);

    // Phase 2c: chunk+split counting-sort fill (LDS position counters)
    k_fill_c<<<gC, 256, 0, stream>>>(edges, cnt2, boff, sdst);

    // Phase 2d: per-position src + cnt_tot, coalesced writes
    k_seg<<<(TT * NN + 255) / 256, 256, 0, stream>>>(cnt2, boff, seg, cnt_tot);

    // Phase 3: MFMA gather-GEMM + wave-cooperative segmented scatter
    dim3 grid(EE / 128, TT);
    k_edge<<<grid, 256, 0, stream>>>(xbf, wT, b, sdst, seg, cnt_tot, wgt, out);
}

// Round 8
// 398.365 us; speedup vs baseline: 1.9188x; 1.1602x over previous
//
#include <hip/hip_runtime.h>
#include <hip/hip_bf16.h>

#define NN 100000
#define DD 64
#define EE 400000
#define TT 5

#define NSPLIT 8                 /* edge-stream splits (inner sort key) */
#define ESL (EE / NSPLIT)        /* 50,000 edges per split slice */
#define CH 32                    /* node chunks per t (exclusive bin ownership) */
#define BPC 3125                 /* NN/CH exact */
#define BPCP 3136                /* padded region: 3136*2B = 6272 = 98 cache lines */
#define C2STRIDE ((size_t)TT * CH * BPCP)   /* u16 elems per split plane */

#define SCAN_TOTAL 500000        /* T*N bins */
#define SCAN_T 256
#define SCAN_PER 1024            /* bins per scan block */
#define SCAN_B 512               /* 512*1024 >= 500000 */

typedef __bf16 bf16x8 __attribute__((ext_vector_type(8)));
typedef float  f32x4  __attribute__((ext_vector_type(4)));

// ws layout (bytes) — total 40,914,240 (<= 40.98 MB proven in R4)
#define OFF_XBF  0u            // N*D ushort      = 12,800,000
#define OFF_WT   12800000u     // T*64*128 ushort = 81,920
#define OFF_CTOT 12881920u     // T*N u32 (cnt_tot) = 2,000,000
#define OFF_WGT  14881920u     // T f32 (pad 64)
#define OFF_CUR  14881984u     // T*N u32 (scan of totals) = 2,000,000
#define OFF_BS   16881984u     // 512 u32 (pad 2048)
#define OFF_BO   16884032u     // 512 u32 (pad 2048)
#define OFF_CNT2 16886080u     // u16[NSPLIT][T][CH][BPCP] = 8,028,160
#define OFF_DST  24914240u     // 2M int (sorted dst) = 8,000,000
#define OFF_SEG  32914240u     // 2M int (seg src)    = 8,000,000 -> 40,914,240

__device__ __forceinline__ unsigned short f2bf(float f) {
    union { float f; unsigned u; } v; v.f = f;
    unsigned u = v.u;
    return (unsigned short)((u + 0x7FFFu + ((u >> 16) & 1u)) >> 16);  // RNE
}

// ---------------- Phase 1: init / convert ----------------
__global__ void k_init(const float* __restrict__ x, const float* __restrict__ W,
                       const float* __restrict__ ea,
                       unsigned short* __restrict__ xbf, unsigned short* __restrict__ wT,
                       float* __restrict__ wgt, float* __restrict__ out) {
    int i = blockIdx.x * blockDim.x + threadIdx.x;   // grid covers N*D exactly
    if (i < NN * DD) {
        out[i] = 0.0f;
        xbf[i] = f2bf(x[i]);
    }
    if (i < TT * 128 * 64) {
        int t = i >> 13;          // /8192
        int rem = i & 8191;
        int d = rem >> 7;         // /128
        int k = rem & 127;
        wT[i] = f2bf(W[t * 8192 + k * 64 + d]);   // wT[t][d][k] = W[t][k][d]
    }
    if (i == 0) {
        float m = -1e30f;
        for (int t = 0; t < TT; t++) m = fmaxf(m, ea[t]);
        float e[TT]; float s = 0.0f;
        for (int t = 0; t < TT; t++) { e[t] = __expf(ea[t] - m); s += e[t]; }
        for (int t = 0; t < TT; t++) wgt[t] = e[t] / s;
    }
}

// ---------------- Phase 2: chunk+split histogram (no global atomics).
// 1280 blocks (5/CU), 49-iter streams. R6/R7 lesson: this kernel is
// latency-bound — block count and chain length are the knobs, not traffic. --
__global__ __launch_bounds__(256) void k_count_c(const int* __restrict__ edges,
                                                 unsigned short* __restrict__ cnt2) {
    const int chunk = blockIdx.x, split = blockIdx.y, t = blockIdx.z;
    const int lo = chunk * BPC;
    __shared__ unsigned hist[BPC];
    for (int i = threadIdx.x; i < BPC; i += 256) hist[i] = 0u;
    __syncthreads();
    const int4* srcp = reinterpret_cast<const int4*>(edges + (size_t)t * 2 * EE + split * ESL);
    for (int i = threadIdx.x; i < ESL / 4; i += 256) {
        int4 v = srcp[i];
        unsigned ux = v.x - lo, uy = v.y - lo, uz = v.z - lo, uw = v.w - lo;
        if (ux < BPC) atomicAdd(&hist[ux], 1u);
        if (uy < BPC) atomicAdd(&hist[uy], 1u);
        if (uz < BPC) atomicAdd(&hist[uz], 1u);
        if (uw < BPC) atomicAdd(&hist[uw], 1u);
    }
    __syncthreads();
    // split-major, line-aligned exclusive region: no cross-block line sharing
    unsigned short* outp = cnt2 + split * C2STRIDE + ((size_t)t * CH + chunk) * BPCP;
    for (int i = threadIdx.x; i < BPC; i += 256) outp[i] = (unsigned short)hist[i];
}

// ---------------- Phase 2b: per-bin totals + exclusive scan (R5-proven shape).
__global__ void k_scan1(const unsigned short* __restrict__ cnt2,
                        unsigned* __restrict__ cnt_tot,
                        unsigned* __restrict__ cur, unsigned* __restrict__ bsum) {
    __shared__ unsigned s[SCAN_T];
    const int b = blockIdx.x, tid = threadIdx.x;
    const int base = b * SCAN_PER + tid * 4;   // bin index (multiple of 4; 500000%4==0)
    unsigned tot[4] = {0u, 0u, 0u, 0u};
    if (base < SCAN_TOTAL) {
#pragma unroll
        for (int j = 0; j < 4; j++) {
            int g = base + j;
            int t = g / NN, n = g - t * NN;
            int chunk = n / BPC, r = n - chunk * BPC;
            size_t o = ((size_t)t * CH + chunk) * BPCP + r;
            unsigned acc = 0u;
#pragma unroll
            for (int sp = 0; sp < NSPLIT; sp++)
                acc += cnt2[sp * C2STRIDE + o];
            tot[j] = acc;
        }
        *reinterpret_cast<uint4*>(cnt_tot + base) = make_uint4(tot[0], tot[1], tot[2], tot[3]);
    }
    const unsigned tsum = tot[0] + tot[1] + tot[2] + tot[3];
    s[tid] = tsum;
    __syncthreads();
    unsigned inc = tsum;
    for (int d = 1; d < SCAN_T; d <<= 1) {
        unsigned add = (tid >= d) ? s[tid - d] : 0u;
        __syncthreads();
        inc += add;
        s[tid] = inc;
        __syncthreads();
    }
    if (tid == SCAN_T - 1) bsum[b] = inc;
    const unsigned p0 = inc - tsum;
    if (base < SCAN_TOTAL) {
        *reinterpret_cast<uint4*>(cur + base) =
            make_uint4(p0, p0 + tot[0], p0 + tot[0] + tot[1], p0 + tot[0] + tot[1] + tot[2]);
    }
}

__global__ void k_scan2(const unsigned* __restrict__ bsum, unsigned* __restrict__ boff) {
    __shared__ unsigned s[SCAN_B];
    const int tid = threadIdx.x;
    const unsigned v = bsum[tid];
    s[tid] = v;
    __syncthreads();
    unsigned inc = v;
    for (int d = 1; d < SCAN_B; d <<= 1) {
        unsigned add = (tid >= d) ? s[tid - d] : 0u;
        __syncthreads();
        inc += add;
        s[tid] = inc;
        __syncthreads();
    }
    boff[tid] = inc - v;
}

// ---------------- Phase 2c: chunk+split fill. LDS position counters seeded
// with cur[bin] + intra-bin split prefix (u16 loads); exclusive ownership. ----
__global__ __launch_bounds__(256) void k_fill_c(const int* __restrict__ edges,
                                                const unsigned short* __restrict__ cnt2,
                                                const unsigned* __restrict__ cur,
                                                const unsigned* __restrict__ boff,
                                                int* __restrict__ sdst) {
    const int chunk = blockIdx.x, split = blockIdx.y, t = blockIdx.z;
    const int lo = chunk * BPC;
    __shared__ unsigned curl[BPC];
    const size_t o0 = ((size_t)t * CH + chunk) * BPCP;
    for (int i = threadIdx.x; i < BPC; i += 256) {
        int g = t * NN + lo + i;
        unsigned base2 = cur[g] + boff[g >> 10];
        for (int sp = 0; sp < split; sp++)        // block-uniform bound (<=7)
            base2 += cnt2[sp * C2STRIDE + o0 + i];
        curl[i] = base2;
    }
    __syncthreads();
    const int* srcp = edges + (size_t)t * 2 * EE + split * ESL;
    const int* dstp = srcp + EE;   // dst plane is +EE from src plane
    for (int i = threadIdx.x; i < ESL / 4; i += 256) {
        int4 v = reinterpret_cast<const int4*>(srcp)[i];
        int e = i * 4;
        unsigned ux = v.x - lo, uy = v.y - lo, uz = v.z - lo, uw = v.w - lo;
        if (ux < BPC) sdst[atomicAdd(&curl[ux], 1u)] = dstp[e + 0];
        if (uy < BPC) sdst[atomicAdd(&curl[uy], 1u)] = dstp[e + 1];
        if (uz < BPC) sdst[atomicAdd(&curl[uz], 1u)] = dstp[e + 2];
        if (uw < BPC) sdst[atomicAdd(&curl[uw], 1u)] = dstp[e + 3];
    }
}

// ---------------- Phase 2d: per-position src (coalesced-ish writes) ----------
__global__ void k_seg(const unsigned* __restrict__ cur, const unsigned* __restrict__ boff,
                      const unsigned* __restrict__ cnt_tot, int* __restrict__ seg) {
    int i = blockIdx.x * blockDim.x + threadIdx.x;
    if (i >= TT * NN) return;
    unsigned start = cur[i] + boff[i >> 10];
    unsigned c = cnt_tot[i];
    int s = i % NN;
    for (unsigned j = 0; j < c; j++) seg[start + j] = s;
}

// ---------------- Phase 3: gather -> MFMA -> wave-cooperative segmented scatter
// (UNCHANGED since R5 — ~185 µs, WRITE 134 MB) ----------------
__global__ __launch_bounds__(256) void k_edge(
    const unsigned short* __restrict__ xbf, const unsigned short* __restrict__ wT,
    const float* __restrict__ b, const int* __restrict__ sdst,
    const int* __restrict__ seg, const unsigned* __restrict__ cnt,
    const float* __restrict__ wgt, float* __restrict__ out) {
    const int t  = blockIdx.y;
    const int e0 = blockIdx.x * 128;

    __shared__ __align__(16) unsigned short Ab[128][136];   // feats tile; reused as f32 proj[128][68]
    __shared__ __align__(16) unsigned short Bb[64][136];    // W_t^T [d][k]
    __shared__ float scale_s[128];
    __shared__ int   src_s[132];                             // padded

    const int tid = threadIdx.x;

    // stage B: W_t^T is 64x128 bf16 contiguous in ws
    {
        const unsigned short* src = wT + (size_t)t * 8192;
        int d = tid >> 2, seg4 = tid & 3;                      // 64B per thread
        const float4* g = reinterpret_cast<const float4*>(src + d * 128 + seg4 * 32);
        float4* l = reinterpret_cast<float4*>(&Bb[d][seg4 * 32]);
#pragma unroll
        for (int c = 0; c < 4; c++) l[c] = g[c];
    }
    // stage A: gather x rows (bf16, 128B each); thread pair per sorted edge
    {
        int e = tid >> 1, half = tid & 1;
        size_t pos = (size_t)t * EE + e0 + e;
        int idx = half ? sdst[pos] : seg[pos];
        const float4* g = reinterpret_cast<const float4*>(xbf + (size_t)idx * 64);
        float4* l = reinterpret_cast<float4*>(&Ab[e][half * 64]);
#pragma unroll
        for (int c = 0; c < 8; c++) l[c] = g[c];
        if (half == 0) {
            src_s[e] = idx;
            scale_s[e] = wgt[t] / (float)cnt[t * NN + idx];   // cnt_tot table is L2-hot
        }
    }
    __syncthreads();

    const int wv = tid >> 6, lane = tid & 63;
    const int m16 = lane & 15, quad = lane >> 4;

    f32x4 acc[2][4];
#pragma unroll
    for (int tm = 0; tm < 2; tm++)
#pragma unroll
        for (int tn = 0; tn < 4; tn++)
            acc[tm][tn] = (f32x4){0.f, 0.f, 0.f, 0.f};

#pragma unroll
    for (int kk = 0; kk < 128; kk += 32) {
        const int kb = kk + quad * 8;
        bf16x8 af[2], bfr[4];
#pragma unroll
        for (int tm = 0; tm < 2; tm++)
            af[tm] = *reinterpret_cast<const bf16x8*>(&Ab[wv * 32 + tm * 16 + m16][kb]);
#pragma unroll
        for (int tn = 0; tn < 4; tn++)
            bfr[tn] = *reinterpret_cast<const bf16x8*>(&Bb[tn * 16 + m16][kb]);
#pragma unroll
        for (int tm = 0; tm < 2; tm++)
#pragma unroll
            for (int tn = 0; tn < 4; tn++)
                acc[tm][tn] = __builtin_amdgcn_mfma_f32_16x16x32_bf16(
                    af[tm], bfr[tn], acc[tm][tn], 0, 0, 0);
    }

    // all waves done reading Ab before we overwrite it with f32 proj
    __syncthreads();

    float bias[4];
#pragma unroll
    for (int tn = 0; tn < 4; tn++) bias[tn] = b[t * 64 + tn * 16 + m16];

    float* proj = reinterpret_cast<float*>(&Ab[0][0]);   // [128][68] f32, stride 68
#pragma unroll
    for (int tm = 0; tm < 2; tm++) {
#pragma unroll
        for (int r = 0; r < 4; r++) {
            const int eloc = wv * 32 + tm * 16 + quad * 4 + r;   // in [wv*32, wv*32+32)
            const float s = scale_s[eloc];
#pragma unroll
            for (int tn = 0; tn < 4; tn++) {
                float v = acc[tm][tn][r] + bias[tn];
                v = v > 0.f ? v : 0.f;
                proj[eloc * 68 + tn * 16 + m16] = v * s;
            }
        }
    }
    // NO barrier: wave wv wrote exactly proj rows [wv*32, wv*32+32) and reads
    // only those below. (src_s/scale_s were synced by the earlier barrier.)

    // wave-cooperative segmented reduce: lane = feature, walk 32 sorted edges,
    // flush one COALESCED 256B atomic burst per segment. Atomics cost their
    // fabric-line footprint, not their op count (R1 vs R3 lesson).
    {
        const int j0 = wv * 32;
        float sum = 0.f;
#pragma unroll
        for (int j = j0; j < j0 + 32; j++) {
            sum += proj[j * 68 + lane];
            const bool flush = (j == j0 + 31) || (src_s[j + 1] != src_s[j]);
            if (flush) {
                atomicAdd(out + (size_t)src_s[j] * 64 + lane, sum);
                sum = 0.f;
            }
        }
    }
}

extern "C" void kernel_launch(void* const* d_in, const int* in_sizes, int n_in,
                              void* d_out, int out_size, void* d_ws, size_t ws_size,
                              hipStream_t stream) {
    const float* x     = (const float*)d_in[0];
    const float* W     = (const float*)d_in[1];
    const float* b     = (const float*)d_in[2];
    const float* ea    = (const float*)d_in[3];
    const int*   edges = (const int*)d_in[4];
    float* out = (float*)d_out;

    char* ws = (char*)d_ws;
    unsigned short* xbf  = (unsigned short*)(ws + OFF_XBF);
    unsigned short* wT   = (unsigned short*)(ws + OFF_WT);
    unsigned* cnt_tot    = (unsigned*)(ws + OFF_CTOT);
    float* wgt           = (float*)(ws + OFF_WGT);
    unsigned* cur        = (unsigned*)(ws + OFF_CUR);
    unsigned* bsum       = (unsigned*)(ws + OFF_BS);
    unsigned* boff       = (unsigned*)(ws + OFF_BO);
    unsigned short* cnt2 = (unsigned short*)(ws + OFF_CNT2);
    int* sdst            = (int*)(ws + OFF_DST);
    int* seg             = (int*)(ws + OFF_SEG);

    // Phase 1: out-zero, x->bf16, W^T, softmax
    k_init<<<(NN * DD) / 256, 256, 0, stream>>>(x, W, ea, xbf, wT, wgt, out);

    // Phase 2: chunk+split histogram counts (1280 blocks, no global atomics)
    dim3 gC(CH, NSPLIT, TT);
    k_count_c<<<gC, 256, 0, stream>>>(edges, cnt2);

    // Phase 2b: per-bin totals + exclusive scan -> cur, boff
    k_scan1<<<SCAN_B, SCAN_T, 0, stream>>>(cnt2, cnt_tot, cur, bsum);
    k_scan2<<<1, SCAN_B, 0, stream>>>(bsum, boff);

    // Phase 2c: chunk+split counting-sort fill (LDS position counters)
    k_fill_c<<<gC, 256, 0, stream>>>(edges, cnt2, cur, boff, sdst);

    // Phase 2d: per-position src
    k_seg<<<(TT * NN + 255) / 256, 256, 0, stream>>>(cur, boff, cnt_tot, seg);

    // Phase 3: MFMA gather-GEMM + wave-cooperative segmented scatter
    dim3 grid(EE / 128, TT);
    k_edge<<<grid, 256, 0, stream>>>(xbf, wT, b, sdst, seg, cnt_tot, wgt, out);
}

// Round 9
// 391.961 us; speedup vs baseline: 1.9501x; 1.0163x over previous
//
#include <hip/hip_runtime.h>
#include <hip/hip_bf16.h>

#define NN 100000
#define DD 64
#define EE 400000
#define TT 5

#define NSPLIT 16                /* edge-stream splits (inner sort key) */
#define ESL (EE / NSPLIT)        /* 25,000 edges per split slice */
#define CH 16                    /* node chunks per t (exclusive bin ownership) */
#define BPC 6250                 /* NN/CH exact */
#define BPCP 6272                /* padded region (98 x 64B lines) */
#define C2STRIDE ((size_t)TT * CH * BPCP)   /* u8 elems per split plane = 501,760 */

#define SCAN_TOTAL 500000        /* T*N bins */
#define SCAN_T 256
#define SCAN_PER 1024            /* bins per scan block */
#define SCAN_B 512               /* 512*1024 >= 500000 */

typedef __bf16 bf16x8 __attribute__((ext_vector_type(8)));
typedef float  f32x4  __attribute__((ext_vector_type(4)));

// ws layout (bytes) — total 40,914,240 (<= 40.98 MB proven in R4)
#define OFF_XBF  0u            // N*D ushort      = 12,800,000
#define OFF_WT   12800000u     // T*64*128 ushort = 81,920
#define OFF_CTOT 12881920u     // T*N u32 (cnt_tot) = 2,000,000
#define OFF_WGT  14881920u     // T f32 (pad 64)
#define OFF_CUR  14881984u     // T*N u32 (scan of totals) = 2,000,000
#define OFF_BS   16881984u     // 512 u32 (pad 2048)
#define OFF_BO   16884032u     // 512 u32 (pad 2048)
#define OFF_CNT2 16886080u     // u8[NSPLIT][T][CH][BPCP] = 8,028,160
#define OFF_DST  24914240u     // 2M int (sorted dst) = 8,000,000
#define OFF_SEG  32914240u     // 2M int (seg src)    = 8,000,000 -> 40,914,240

__device__ __forceinline__ unsigned short f2bf(float f) {
    union { float f; unsigned u; } v; v.f = f;
    unsigned u = v.u;
    return (unsigned short)((u + 0x7FFFu + ((u >> 16) & 1u)) >> 16);  // RNE
}

// ---------------- Phase 1: init / convert ----------------
__global__ void k_init(const float* __restrict__ x, const float* __restrict__ W,
                       const float* __restrict__ ea,
                       unsigned short* __restrict__ xbf, unsigned short* __restrict__ wT,
                       float* __restrict__ wgt, float* __restrict__ out) {
    int i = blockIdx.x * blockDim.x + threadIdx.x;   // grid covers N*D exactly
    if (i < NN * DD) {
        out[i] = 0.0f;
        xbf[i] = f2bf(x[i]);
    }
    if (i < TT * 128 * 64) {
        int t = i >> 13;          // /8192
        int rem = i & 8191;
        int d = rem >> 7;         // /128
        int k = rem & 127;
        wT[i] = f2bf(W[t * 8192 + k * 64 + d]);   // wT[t][d][k] = W[t][k][d]
    }
    if (i == 0) {
        float m = -1e30f;
        for (int t = 0; t < TT; t++) m = fmaxf(m, ea[t]);
        float e[TT]; float s = 0.0f;
        for (int t = 0; t < TT; t++) { e[t] = __expf(ea[t] - m); s += e[t]; }
        for (int t = 0; t < TT; t++) wgt[t] = e[t] / s;
    }
}

// ---------------- Phase 2: chunk+split histogram (no global atomics).
// CH=16 x NSPLIT=16: 1280 blocks ALL co-resident (5/CU, 25 KB LDS), 24-iter
// chains, half the redundant visits of R8. u8 counts: per-(t,src,split) is
// Poisson(0.25) — 255 is unreachable. -----------------------------------------
__global__ __launch_bounds__(256) void k_count_c(const int* __restrict__ edges,
                                                 unsigned char* __restrict__ cnt2) {
    const int chunk = blockIdx.x, split = blockIdx.y, t = blockIdx.z;
    const int lo = chunk * BPC;
    __shared__ unsigned hist[BPC];
    for (int i = threadIdx.x; i < BPC; i += 256) hist[i] = 0u;
    __syncthreads();
    const int4* srcp = reinterpret_cast<const int4*>(edges + (size_t)t * 2 * EE + split * ESL);
    for (int i = threadIdx.x; i < ESL / 4; i += 256) {
        int4 v = srcp[i];
        unsigned ux = v.x - lo, uy = v.y - lo, uz = v.z - lo, uw = v.w - lo;
        if (ux < BPC) atomicAdd(&hist[ux], 1u);
        if (uy < BPC) atomicAdd(&hist[uy], 1u);
        if (uz < BPC) atomicAdd(&hist[uz], 1u);
        if (uw < BPC) atomicAdd(&hist[uw], 1u);
    }
    __syncthreads();
    // split-major, line-aligned exclusive region: no cross-block line sharing
    unsigned char* outp = cnt2 + split * C2STRIDE + ((size_t)t * CH + chunk) * BPCP;
    for (int i = threadIdx.x; i < BPC; i += 256) outp[i] = (unsigned char)hist[i];
}

// ---------------- Phase 2b: per-bin totals (sum of 16 u8 planes) + scan ------
__global__ void k_scan1(const unsigned char* __restrict__ cnt2,
                        unsigned* __restrict__ cnt_tot,
                        unsigned* __restrict__ cur, unsigned* __restrict__ bsum) {
    __shared__ unsigned s[SCAN_T];
    const int b = blockIdx.x, tid = threadIdx.x;
    const int base = b * SCAN_PER + tid * 4;   // bin index (500000 % 4 == 0)
    unsigned tot[4] = {0u, 0u, 0u, 0u};
    if (base < SCAN_TOTAL) {
#pragma unroll
        for (int j = 0; j < 4; j++) {
            int g = base + j;
            int t = g / NN, n = g - t * NN;
            int chunk = n / BPC, r = n - chunk * BPC;
            size_t o = ((size_t)t * CH + chunk) * BPCP + r;
            unsigned acc = 0u;
#pragma unroll
            for (int sp = 0; sp < NSPLIT; sp++)
                acc += cnt2[sp * C2STRIDE + o];
            tot[j] = acc;
        }
        *reinterpret_cast<uint4*>(cnt_tot + base) = make_uint4(tot[0], tot[1], tot[2], tot[3]);
    }
    const unsigned tsum = tot[0] + tot[1] + tot[2] + tot[3];
    s[tid] = tsum;
    __syncthreads();
    unsigned inc = tsum;
    for (int d = 1; d < SCAN_T; d <<= 1) {
        unsigned add = (tid >= d) ? s[tid - d] : 0u;
        __syncthreads();
        inc += add;
        s[tid] = inc;
        __syncthreads();
    }
    if (tid == SCAN_T - 1) bsum[b] = inc;
    const unsigned p0 = inc - tsum;
    if (base < SCAN_TOTAL) {
        *reinterpret_cast<uint4*>(cur + base) =
            make_uint4(p0, p0 + tot[0], p0 + tot[0] + tot[1], p0 + tot[0] + tot[1] + tot[2]);
    }
}

__global__ void k_scan2(const unsigned* __restrict__ bsum, unsigned* __restrict__ boff) {
    __shared__ unsigned s[SCAN_B];
    const int tid = threadIdx.x;
    const unsigned v = bsum[tid];
    s[tid] = v;
    __syncthreads();
    unsigned inc = v;
    for (int d = 1; d < SCAN_B; d <<= 1) {
        unsigned add = (tid >= d) ? s[tid - d] : 0u;
        __syncthreads();
        inc += add;
        s[tid] = inc;
        __syncthreads();
    }
    boff[tid] = inc - v;
}

// ---------------- Phase 2c: chunk+split fill. LDS position counters seeded
// with cur[bin] + intra-bin split prefix (<=15 coalesced u8 loads/bin). -------
__global__ __launch_bounds__(256) void k_fill_c(const int* __restrict__ edges,
                                                const unsigned char* __restrict__ cnt2,
                                                const unsigned* __restrict__ cur,
                                                const unsigned* __restrict__ boff,
                                                int* __restrict__ sdst) {
    const int chunk = blockIdx.x, split = blockIdx.y, t = blockIdx.z;
    const int lo = chunk * BPC;
    __shared__ unsigned curl[BPC];
    const size_t o0 = ((size_t)t * CH + chunk) * BPCP;
    for (int i = threadIdx.x; i < BPC; i += 256) {
        int g = t * NN + lo + i;
        unsigned base2 = cur[g] + boff[g >> 10];
        for (int sp = 0; sp < split; sp++)        // block-uniform bound
            base2 += cnt2[(size_t)sp * C2STRIDE + o0 + i];
        curl[i] = base2;
    }
    __syncthreads();
    const int* srcp = edges + (size_t)t * 2 * EE + split * ESL;
    const int* dstp = srcp + EE;   // dst plane is +EE from src plane
    for (int i = threadIdx.x; i < ESL / 4; i += 256) {
        int4 v = reinterpret_cast<const int4*>(srcp)[i];
        int e = i * 4;
        unsigned ux = v.x - lo, uy = v.y - lo, uz = v.z - lo, uw = v.w - lo;
        if (ux < BPC) sdst[atomicAdd(&curl[ux], 1u)] = dstp[e + 0];
        if (uy < BPC) sdst[atomicAdd(&curl[uy], 1u)] = dstp[e + 1];
        if (uz < BPC) sdst[atomicAdd(&curl[uz], 1u)] = dstp[e + 2];
        if (uw < BPC) sdst[atomicAdd(&curl[uw], 1u)] = dstp[e + 3];
    }
}

// ---------------- Phase 2d: per-position src (coalesced-ish writes) ----------
__global__ void k_seg(const unsigned* __restrict__ cur, const unsigned* __restrict__ boff,
                      const unsigned* __restrict__ cnt_tot, int* __restrict__ seg) {
    int i = blockIdx.x * blockDim.x + threadIdx.x;
    if (i >= TT * NN) return;
    unsigned start = cur[i] + boff[i >> 10];
    unsigned c = cnt_tot[i];
    int s = i % NN;
    for (unsigned j = 0; j < c; j++) seg[start + j] = s;
}

// ---------------- Phase 3: gather -> MFMA -> wave-cooperative segmented scatter.
// R9: B-fragments read DIRECTLY from global wT (16 KB slice, L1-resident) —
// drops Bb (17.4 KB LDS) -> 35.9 KB/block -> 4 blocks/CU (was 3). -------------
__global__ __launch_bounds__(256) void k_edge(
    const unsigned short* __restrict__ xbf, const unsigned short* __restrict__ wT,
    const float* __restrict__ b, const int* __restrict__ sdst,
    const int* __restrict__ seg, const unsigned* __restrict__ cnt,
    const float* __restrict__ wgt, float* __restrict__ out) {
    const int t  = blockIdx.y;
    const int e0 = blockIdx.x * 128;

    __shared__ __align__(16) unsigned short Ab[128][136];   // feats tile; reused as f32 proj[128][68]
    __shared__ float scale_s[128];
    __shared__ int   src_s[132];                             // padded

    const int tid = threadIdx.x;

    // stage A: gather x rows (bf16, 128B each); thread pair per sorted edge
    {
        int e = tid >> 1, half = tid & 1;
        size_t pos = (size_t)t * EE + e0 + e;
        int idx = half ? sdst[pos] : seg[pos];
        const float4* g = reinterpret_cast<const float4*>(xbf + (size_t)idx * 64);
        float4* l = reinterpret_cast<float4*>(&Ab[e][half * 64]);
#pragma unroll
        for (int c = 0; c < 8; c++) l[c] = g[c];
        if (half == 0) {
            src_s[e] = idx;
            scale_s[e] = wgt[t] / (float)cnt[t * NN + idx];   // cnt_tot table is L2-hot
        }
    }
    __syncthreads();

    const int wv = tid >> 6, lane = tid & 63;
    const int m16 = lane & 15, quad = lane >> 4;
    const unsigned short* wrow = wT + (size_t)t * 8192;      // [d][k], 64x128

    f32x4 acc[2][4];
#pragma unroll
    for (int tm = 0; tm < 2; tm++)
#pragma unroll
        for (int tn = 0; tn < 4; tn++)
            acc[tm][tn] = (f32x4){0.f, 0.f, 0.f, 0.f};

#pragma unroll
    for (int kk = 0; kk < 128; kk += 32) {
        const int kb = kk + quad * 8;
        bf16x8 af[2], bfr[4];
#pragma unroll
        for (int tm = 0; tm < 2; tm++)
            af[tm] = *reinterpret_cast<const bf16x8*>(&Ab[wv * 32 + tm * 16 + m16][kb]);
#pragma unroll
        for (int tn = 0; tn < 4; tn++)
            bfr[tn] = *reinterpret_cast<const bf16x8*>(wrow + (tn * 16 + m16) * 128 + kb);
#pragma unroll
        for (int tm = 0; tm < 2; tm++)
#pragma unroll
            for (int tn = 0; tn < 4; tn++)
                acc[tm][tn] = __builtin_amdgcn_mfma_f32_16x16x32_bf16(
                    af[tm], bfr[tn], acc[tm][tn], 0, 0, 0);
    }

    // all waves done reading Ab before we overwrite it with f32 proj
    __syncthreads();

    float bias[4];
#pragma unroll
    for (int tn = 0; tn < 4; tn++) bias[tn] = b[t * 64 + tn * 16 + m16];

    float* proj = reinterpret_cast<float*>(&Ab[0][0]);   // [128][68] f32, stride 68
#pragma unroll
    for (int tm = 0; tm < 2; tm++) {
#pragma unroll
        for (int r = 0; r < 4; r++) {
            const int eloc = wv * 32 + tm * 16 + quad * 4 + r;   // in [wv*32, wv*32+32)
            const float s = scale_s[eloc];
#pragma unroll
            for (int tn = 0; tn < 4; tn++) {
                float v = acc[tm][tn][r] + bias[tn];
                v = v > 0.f ? v : 0.f;
                proj[eloc * 68 + tn * 16 + m16] = v * s;
            }
        }
    }
    // NO barrier: wave wv wrote exactly proj rows [wv*32, wv*32+32) and reads
    // only those below. (src_s/scale_s were synced by the earlier barrier.)

    // wave-cooperative segmented reduce: lane = feature, walk 32 sorted edges,
    // flush one COALESCED 256B atomic burst per segment. Atomics cost their
    // fabric-line footprint, not their op count (R1 vs R3 lesson).
    {
        const int j0 = wv * 32;
        float sum = 0.f;
#pragma unroll
        for (int j = j0; j < j0 + 32; j++) {
            sum += proj[j * 68 + lane];
            const bool flush = (j == j0 + 31) || (src_s[j + 1] != src_s[j]);
            if (flush) {
                atomicAdd(out + (size_t)src_s[j] * 64 + lane, sum);
                sum = 0.f;
            }
        }
    }
}

extern "C" void kernel_launch(void* const* d_in, const int* in_sizes, int n_in,
                              void* d_out, int out_size, void* d_ws, size_t ws_size,
                              hipStream_t stream) {
    const float* x     = (const float*)d_in[0];
    const float* W     = (const float*)d_in[1];
    const float* b     = (const float*)d_in[2];
    const float* ea    = (const float*)d_in[3];
    const int*   edges = (const int*)d_in[4];
    float* out = (float*)d_out;

    char* ws = (char*)d_ws;
    unsigned short* xbf  = (unsigned short*)(ws + OFF_XBF);
    unsigned short* wT   = (unsigned short*)(ws + OFF_WT);
    unsigned* cnt_tot    = (unsigned*)(ws + OFF_CTOT);
    float* wgt           = (float*)(ws + OFF_WGT);
    unsigned* cur        = (unsigned*)(ws + OFF_CUR);
    unsigned* bsum       = (unsigned*)(ws + OFF_BS);
    unsigned* boff       = (unsigned*)(ws + OFF_BO);
    unsigned char* cnt2  = (unsigned char*)(ws + OFF_CNT2);
    int* sdst            = (int*)(ws + OFF_DST);
    int* seg             = (int*)(ws + OFF_SEG);

    // Phase 1: out-zero, x->bf16, W^T, softmax
    k_init<<<(NN * DD) / 256, 256, 0, stream>>>(x, W, ea, xbf, wT, wgt, out);

    // Phase 2: chunk+split histogram counts (1280 blocks, all co-resident)
    dim3 gC(CH, NSPLIT, TT);
    k_count_c<<<gC, 256, 0, stream>>>(edges, cnt2);

    // Phase 2b: per-bin totals + exclusive scan -> cur, boff
    k_scan1<<<SCAN_B, SCAN_T, 0, stream>>>(cnt2, cnt_tot, cur, bsum);
    k_scan2<<<1, SCAN_B, 0, stream>>>(bsum, boff);

    // Phase 2c: chunk+split counting-sort fill (LDS position counters)
    k_fill_c<<<gC, 256, 0, stream>>>(edges, cnt2, cur, boff, sdst);

    // Phase 2d: per-position src
    k_seg<<<(TT * NN + 255) / 256, 256, 0, stream>>>(cur, boff, cnt_tot, seg);

    // Phase 3: MFMA gather-GEMM + wave-cooperative segmented scatter
    dim3 grid(EE / 128, TT);
    k_edge<<<grid, 256, 0, stream>>>(xbf, wT, b, sdst, seg, cnt_tot, wgt, out);
}